// Round 1
// baseline (57.341 us; speedup 1.0000x reference)
//
#include <hip/hip_runtime.h>
#include <hip/hip_bf16.h>

// BPMLL loss, factorized:
//   inner[b] = (sum_{j: t=0} exp(x_j)) * (sum_{i: t=1} exp(-x_i))
//   length[b] = npos * nneg
//   out = sum_b inner[b] / length[b]

#define B_DIM 128
#define L_DIM 1024

__global__ void bpmll_zero_out(float* out) { out[0] = 0.0f; }

__global__ __launch_bounds__(256) void bpmll_kernel(const float* __restrict__ inp,
                                                    const int* __restrict__ tgt,
                                                    float* __restrict__ out) {
    const int b = blockIdx.x;      // batch row
    const int t = threadIdx.x;     // 0..255, 4 elements each

    const float4* in4 = (const float4*)(inp + (size_t)b * L_DIM);
    const int4*   tg4 = (const int4*)(tgt + (size_t)b * L_DIM);

    float4 x = in4[t];
    int4   y = tg4[t];

    float s_neg = 0.0f;   // sum exp(x) over negatives
    float s_pos = 0.0f;   // sum exp(-x) over positives
    int   npos  = 0;

    if (y.x == 1) { s_pos += __expf(-x.x) * 0.0f + expf(-x.x); npos++; } else { s_neg += expf(x.x); }
    if (y.y == 1) { s_pos += expf(-x.y); npos++; } else { s_neg += expf(x.y); }
    if (y.z == 1) { s_pos += expf(-x.z); npos++; } else { s_neg += expf(x.z); }
    if (y.w == 1) { s_pos += expf(-x.w); npos++; } else { s_neg += expf(x.w); }

    // wave-64 reduction
    #pragma unroll
    for (int off = 32; off > 0; off >>= 1) {
        s_neg += __shfl_down(s_neg, off);
        s_pos += __shfl_down(s_pos, off);
        npos  += __shfl_down(npos,  off);
    }

    __shared__ float sh_neg[4], sh_pos[4];
    __shared__ int   sh_np[4];
    const int wave = t >> 6;
    if ((t & 63) == 0) {
        sh_neg[wave] = s_neg;
        sh_pos[wave] = s_pos;
        sh_np[wave]  = npos;
    }
    __syncthreads();

    if (t == 0) {
        float tn = sh_neg[0] + sh_neg[1] + sh_neg[2] + sh_neg[3];
        float tp = sh_pos[0] + sh_pos[1] + sh_pos[2] + sh_pos[3];
        int   np = sh_np[0] + sh_np[1] + sh_np[2] + sh_np[3];
        int   nn = L_DIM - np;
        float len = (float)np * (float)nn;
        float loss = (len > 0.0f) ? (tn * tp) / len : 0.0f;
        atomicAdd(out, loss);
    }
}

extern "C" void kernel_launch(void* const* d_in, const int* in_sizes, int n_in,
                              void* d_out, int out_size, void* d_ws, size_t ws_size,
                              hipStream_t stream) {
    const float* inp = (const float*)d_in[0];
    const int*   tgt = (const int*)d_in[1];
    float* out = (float*)d_out;

    bpmll_zero_out<<<1, 1, 0, stream>>>(out);
    bpmll_kernel<<<B_DIM, 256, 0, stream>>>(inp, tgt, out);
}